// Round 5
// baseline (181.989 us; speedup 1.0000x reference)
//
#include <hip/hip_runtime.h>
#include <math.h>

// FP contraction off: every f32 op is an exactly-rounded IEEE op in fixed
// order -> geometry is bit-identical across pass1 / pass2 / exact-repair
// paths and matches the numpy float32 reference.
#pragma clang fp contract(off)

#define NUM_CLASSES 80
#define TB 64   // targets per image
#define NB 8    // batch
#define BAND 16 // est ulp-band: est err <= ~4 ulp, mis-order needs <= ~10 ulp

// IoU geometry (inter, union) — identical everywhere.
__device__ __forceinline__ void geomf(const float4 bb, float at,
                                      const float4 av, float aar,
                                      float& inter, float& u) {
  float w = fminf(bb.z, av.z) - fmaxf(bb.x, av.x);
  float h = fminf(bb.w, av.w) - fmaxf(bb.y, av.y);
  w = fmaxf(w, 0.0f);
  h = fmaxf(h, 0.0f);
  inter = w * h;
  u = (at + aar) - inter;
}

// pass 0: cxcywh -> xyxy; zero gmax bits (IoU >= 0 -> 0 is max-identity).
__global__ void pass0(const float* __restrict__ tgt,
                      float4* __restrict__ boxes,
                      int* __restrict__ gmaxbits) {
  int i = blockIdx.x * blockDim.x + threadIdx.x;
  if (i < NB * TB) {
    float cx = tgt[i*4+0], cy = tgt[i*4+1], w = tgt[i*4+2], h = tgt[i*4+3];
    boxes[i] = make_float4(cx - 0.5f*w, cy - 0.5f*h, cx + 0.5f*w, cy + 0.5f*h);
    gmaxbits[i] = 0;
  }
}

// pass 1: gmax[b][t] = max_a round(i/u).  lane = t, wave streams anchors
// wave-uniformly (scalar loads). Running max on est with band flag; rare
// exact f64 rescan; one f32 div per lane-chunk; LDS pre-reduce per block.
#define P1_WCHUNK 128
__global__ __launch_bounds__(256) void pass1(const float4* __restrict__ anchors,
                                             const float4* __restrict__ boxes,
                                             int* __restrict__ gmaxbits, int A) {
  int b = blockIdx.y;
  int tid = threadIdx.x;
  int lane = tid & 63;
  int wv = __builtin_amdgcn_readfirstlane(tid >> 6);
  int a0 = (blockIdx.x * 4 + wv) * P1_WCHUNK;

  __shared__ int sg[TB];
  if (tid < TB) sg[tid] = 0;
  __syncthreads();

  float4 bb = boxes[b * TB + lane];
  float at = (bb.z - bb.x) * (bb.w - bb.y);

  // 4 independent accumulator chains (est, winning anchor index)
  float be0 = 1e-30f, be1 = 1e-30f, be2 = 1e-30f, be3 = 1e-30f;
  int bx0 = a0, bx1 = a0, bx2 = a0, bx3 = a0;
  int fl = 0;

#pragma unroll 2
  for (int j = 0; j < P1_WCHUNK; j += 4) {
#define STEP(Q, BE, BX)                                                  \
    {                                                                    \
      int a = min(a0 + j + Q, A - 1);                                    \
      float4 av = anchors[a];              /* uniform -> s_load */       \
      float aar = (av.z - av.x) * (av.w - av.y);                         \
      float inter, u;                                                    \
      geomf(bb, at, av, aar, inter, u);                                  \
      float est = inter * __builtin_amdgcn_rcpf(u);                      \
      int db = __float_as_int(est) - __float_as_int(BE);                 \
      fl |= ((unsigned)(db + BAND) <= 2u * BAND) ? 1 : 0;                \
      if (est > BE) { BE = est; BX = a; }                                \
    }
    STEP(0, be0, bx0)
    STEP(1, be1, bx1)
    STEP(2, be2, bx2)
    STEP(3, be3, bx3)
#undef STEP
  }
#define COMB(BE, BX)                                                     \
  { int db = __float_as_int(BE) - __float_as_int(be0);                   \
    fl |= ((unsigned)(db + BAND) <= 2u * BAND) ? 1 : 0;                  \
    if (BE > be0) { be0 = BE; bx0 = BX; } }
  COMB(be1, bx1) COMB(be2, bx2) COMB(be3, bx3)
#undef COMB

  float M;
  if (fl) {
    // exact f64 rescan of this chunk (rare): f32 geometry, exact cross-mult
    double id = 0.0, ud = 1.0;
    for (int j = 0; j < P1_WCHUNK; ++j) {
      int a = min(a0 + j, A - 1);
      float4 av = anchors[a];
      float aar = (av.z - av.x) * (av.w - av.y);
      float inter, u;
      geomf(bb, at, av, aar, inter, u);
      if ((double)inter * ud > id * (double)u) { id = (double)inter; ud = (double)u; }
    }
    M = (float)id / (float)ud;
  } else {
    float4 av = anchors[bx0];
    float aar = (av.z - av.x) * (av.w - av.y);
    float inter, u;
    geomf(bb, at, av, aar, inter, u);
    M = inter / u;   // one correctly-rounded div per chunk
  }
  atomicMax(&sg[lane], __float_as_int(M));
  __syncthreads();
  if (tid < TB)
    atomicMax(gmaxbits + b * TB + tid, sg[tid]);
}

// pass 2: per (b, anchor): est-based argmax + band flag + highest-window;
// flagged/candidate anchors take the exact f64 path (round-4 logic).
#define P2_K 2
__global__ __launch_bounds__(256) void pass2(const float4* __restrict__ anchors,
                                             const float4* __restrict__ boxes,
                                             const int* __restrict__ gmaxbits,
                                             const int* __restrict__ labels,
                                             float* __restrict__ out, int A) {
  int b = blockIdx.y;
  __shared__ float4 sb[TB];
  __shared__ float4 sm[TB];  // {at, asfloat(lo), asfloat(range), asfloat(gbits)}
  __shared__ int    sl[TB];
  int tid = threadIdx.x;
  if (tid < TB) {
    float4 bv = boxes[b * TB + tid];
    sb[tid] = bv;
    int gb = gmaxbits[b * TB + tid];
    int lo = gb - BAND; if (lo < 0) lo = 0;
    int range = (gb + BAND) - lo;
    sm[tid] = make_float4((bv.z - bv.x) * (bv.w - bv.y),
                          __int_as_float(lo), __int_as_float(range),
                          __int_as_float(gb));
    sl[tid] = labels[b * TB + tid];
  }
  __syncthreads();

  int abase = blockIdx.x * (P2_K * 256) + tid;

  float4 av[P2_K]; float aar[P2_K];
  float be[P2_K]; int mid[P2_K]; int fl[P2_K]; int hc[P2_K];
#pragma unroll
  for (int k = 0; k < P2_K; ++k) {
    int a = min(abase + k * 256, A - 1);  // dup compute; store guarded below
    av[k]  = anchors[a];
    aar[k] = (av[k].z - av[k].x) * (av[k].w - av[k].y);
    be[k] = 1e-30f; mid[k] = 0; fl[k] = 0; hc[k] = 0;
  }

#pragma unroll 4
  for (int t = 0; t < TB; ++t) {
    float4 bbv = sb[t];
    float4 mv  = sm[t];
    int lo = __float_as_int(mv.y), range = __float_as_int(mv.z);
#pragma unroll
    for (int k = 0; k < P2_K; ++k) {
      float inter, u;
      geomf(bbv, mv.x, av[k], aar[k], inter, u);
      float est = inter * __builtin_amdgcn_rcpf(u);
      int eb = __float_as_int(est);
      int db = eb - __float_as_int(be[k]);
      fl[k] |= ((unsigned)(db + BAND) <= 2u * BAND) ? 1 : 0;
      hc[k] |= ((unsigned)(eb - lo) <= (unsigned)range) ? 1 : 0;
      if (est > be[k]) { be[k] = est; mid[k] = t; }  // strict > == first occ.
    }
  }

#pragma unroll
  for (int k = 0; k < P2_K; ++k) {
    int a = abase + k * 256;
    if (a >= A) continue;

    float M; int m; bool high;
    if (fl[k] | hc[k]) {
      // ---- exact f64 path (round-4 logic, proven) ----
      double id = 0.0, ud = 1.0; int ts = 0; bool flag2 = false, hix = false;
      for (int t = 0; t < TB; ++t) {
        float inter, u;
        geomf(sb[t], sm[t].x, av[k], aar[k], inter, u);
        double i_d = (double)inter, u_d = (double)u;
        double p1 = i_d * ud, p2 = id * u_d;       // exact 24x24-bit products
        double dd = fabs(p2 - p1), pm = fmax(p1, p2);
        flag2 = flag2 | ((dd != 0.0) & (dd <= pm * 2.384185791015625e-07));
        if (p1 > p2) { id = i_d; ud = u_d; ts = t; }
        int gbt = __float_as_int(sm[t].w);
        double glo; bool cl;
        if (gbt == 0) { glo = -1.0; cl = true; }
        else {
          float g = __int_as_float(gbt), gp = __int_as_float(gbt - 1);
          glo = 0.5 * ((double)g + (double)gp);    // exact
          cl  = ((gbt & 1) == 0);
        }
        double ph = glo * u_d;
        hix = hix | (i_d > ph) | (cl & (i_d == ph));
      }
      M = (float)id / (float)ud;
      m = ts;
      if (flag2) {
        // first t whose rounded v == M (np argmax first-occurrence)
        int Mb = __float_as_int(M);
        double Mlo; bool clM;
        if (Mb == 0) { Mlo = -1.0; clM = true; }
        else {
          float Mp = __int_as_float(Mb - 1);
          Mlo = 0.5 * ((double)M + (double)Mp);
          clM = ((Mb & 1) == 0);
        }
        for (int t = 0; t < TB; ++t) {
          float inter, u;
          geomf(sb[t], sm[t].x, av[k], aar[k], inter, u);
          double p = Mlo * (double)u;
          if (((double)inter > p) | (clM & ((double)inter == p))) { m = t; break; }
        }
      }
      high = hix;
    } else {
      m = mid[k];
      float inter, u;
      geomf(sb[m], sm[m].x, av[k], aar[k], inter, u);
      M = inter / u;      // winner's correctly-rounded value
      high = false;       // no window hit -> no t with round(v)==g
    }

    int lab;
    if (high)           lab = 1;   // low-quality matches become positives
    else if (M >= 0.5f) lab = 1;
    else if (M >= 0.4f) lab = -1;
    else                lab = 0;

    int out_label = (lab == 1) ? sl[m] : ((lab == 0) ? NUM_CLASSES : -1);
    out[(size_t)b * A + a] = (float)out_label;

    float4 mb = sb[m];
    float sw = av[k].z - av[k].x, sh2 = av[k].w - av[k].y;
    float sx = av[k].x + 0.5f*sw, sy = av[k].y + 0.5f*sh2;
    float tw = mb.z - mb.x,       th = mb.w - mb.y;
    float tx = mb.x + 0.5f*tw,    ty = mb.y + 0.5f*th;
    float4 d;
    d.x = (tx - sx) / sw;
    d.y = (ty - sy) / sh2;
    d.z = logf(tw / sw);
    d.w = logf(th / sh2);
    *(float4*)(out + (size_t)NB * A + ((size_t)b * A + a) * 4) = d;
  }
}

extern "C" void kernel_launch(void* const* d_in, const int* in_sizes, int n_in,
                              void* d_out, int out_size, void* d_ws, size_t ws_size,
                              hipStream_t stream) {
  const float* anchors    = (const float*)d_in[0];
  const float* tgt_boxes  = (const float*)d_in[1];
  const int*   tgt_labels = (const int*)d_in[2];
  int A = in_sizes[0] / 4;

  float*  ws       = (float*)d_ws;
  float4* boxes    = (float4*)ws;                  // NB*TB float4
  int*    gmaxbits = (int*)(ws + NB * TB * 4);     // NB*TB int
  float*  out      = (float*)d_out;

  pass0<<<2, 256, 0, stream>>>(tgt_boxes, boxes, gmaxbits);
  dim3 g1((A + 4 * P1_WCHUNK - 1) / (4 * P1_WCHUNK), NB);
  pass1<<<g1, 256, 0, stream>>>((const float4*)anchors, boxes, gmaxbits, A);
  dim3 g2((A + P2_K * 256 - 1) / (P2_K * 256), NB);
  pass2<<<g2, 256, 0, stream>>>((const float4*)anchors, boxes, gmaxbits,
                                tgt_labels, out, A);
}

// Round 6
// 101.316 us; speedup vs baseline: 1.7963x; 1.7963x over previous
//
#include <hip/hip_runtime.h>
#include <math.h>

// FP contraction off: every f32 op is an exactly-rounded IEEE op in fixed
// order -> IoU is bit-identical in K1 and K3's rescan, and identical to the
// numpy float32 reference (per-element rounded div, then max/argmax).
#pragma clang fp contract(off)

#define NUM_CLASSES 80
#define TB 64      // targets per image
#define NB 8       // batch
#define K1_K 2
#define K1_APB (K1_K * 256)   // 512 anchors per block

// The one-and-only IoU expression (must be identical in K1 and K3).
__device__ __forceinline__ float iou_exact(const float4 bb, float at,
                                           const float4 av, float aar) {
  float w = fminf(bb.z, av.z) - fmaxf(bb.x, av.x);
  float h = fminf(bb.w, av.w) - fmaxf(bb.y, av.y);
  w = fmaxf(w, 0.0f);
  h = fmaxf(h, 0.0f);
  float inter = w * h;
  float u = (at + aar) - inter;
  return inter / u;   // correctly-rounded IEEE f32 div
}

// gfx9 wave64 max-reduce on DPP (pure VALU). Valid for non-negative x
// (bound_ctrl=1 feeds 0.0f). Result in lane 63. (Proven in round 3.)
__device__ __forceinline__ float wave_max_nonneg(float x) {
  int v = __float_as_int(x);
#define DPPMAX(ctrl)                                                         \
  v = __float_as_int(fmaxf(__int_as_float(v),                               \
      __int_as_float(__builtin_amdgcn_update_dpp(0, v, ctrl, 0xf, 0xf, true))));
  DPPMAX(0x111);  // row_shr:1
  DPPMAX(0x112);  // row_shr:2
  DPPMAX(0x114);  // row_shr:4
  DPPMAX(0x118);  // row_shr:8
  DPPMAX(0x142);  // row_bcast:15
  DPPMAX(0x143);  // row_bcast:31
#undef DPPMAX
  return __int_as_float(v);
}

// pass 0: cxcywh -> xyxy.
__global__ void pass0(const float* __restrict__ tgt, float4* __restrict__ boxes) {
  int i = blockIdx.x * blockDim.x + threadIdx.x;
  if (i < NB * TB) {
    float cx = tgt[i*4+0], cy = tgt[i*4+1], w = tgt[i*4+2], h = tgt[i*4+3];
    boxes[i] = make_float4(cx - 0.5f*w, cy - 0.5f*h, cx + 0.5f*w, cy + 0.5f*h);
  }
}

// K1 (the heavy pass, round-3 body + fused per-t block max):
// per (b, anchor): argmax/max over t with plain div; per t, DPP wave-max ->
// LDS block max -> bmax[b][t][block]. Writes deltas (final) and a label-code
// word (temporary) into out.
__global__ __launch_bounds__(256) void k1(const float4* __restrict__ anchors,
                                          const float4* __restrict__ boxes,
                                          const int* __restrict__ labels,
                                          int* __restrict__ bmax,
                                          float* __restrict__ out,
                                          int A, int NBLK) {
  int b = blockIdx.y;
  __shared__ float4 sb[TB];
  __shared__ float  sa[TB];
  __shared__ int    sl[TB];
  __shared__ int    sg[TB];
  int tid = threadIdx.x;
  if (tid < TB) {
    float4 bv = boxes[b * TB + tid];
    sb[tid] = bv;
    sa[tid] = (bv.z - bv.x) * (bv.w - bv.y);
    sl[tid] = labels[b * TB + tid];
    sg[tid] = 0;
  }
  __syncthreads();

  int abase = blockIdx.x * K1_APB + tid;
  float4 av[K1_K]; float aar[K1_K]; float best[K1_K]; int mid[K1_K];
#pragma unroll
  for (int k = 0; k < K1_K; ++k) {
    int a = min(abase + k * 256, A - 1);  // dup clamp: benign for max; stores guarded
    av[k]  = anchors[a];
    aar[k] = (av[k].z - av[k].x) * (av[k].w - av[k].y);
    best[k] = -1.0f; mid[k] = 0;
  }

#pragma unroll 4
  for (int t = 0; t < TB; ++t) {
    float4 bb = sb[t];
    float  at = sa[t];
    float v0 = iou_exact(bb, at, av[0], aar[0]);
    float v1 = iou_exact(bb, at, av[1], aar[1]);
    if (v0 > best[0]) { best[0] = v0; mid[0] = t; }  // strict > = first occurrence
    if (v1 > best[1]) { best[1] = v1; mid[1] = t; }
    float wm = wave_max_nonneg(fmaxf(v0, v1));       // max over this wave's 128 anchors
    if ((tid & 63) == 63)
      atomicMax(&sg[t], __float_as_int(wm));         // IoU>=0: int order == float order
  }
  __syncthreads();
  if (tid < TB)
    bmax[(b * TB + tid) * NBLK + blockIdx.x] = sg[tid];

#pragma unroll
  for (int k = 0; k < K1_K; ++k) {
    int a = abase + k * 256;
    if (a >= A) continue;
    float M = best[k];
    int m = mid[k];
    int lab = (M >= 0.5f) ? 1 : ((M >= 0.4f) ? -1 : 0);   // thresholds on exact M
    // temporary code word: positive-label | (lab+1); final label needs `high`
    out[(size_t)b * A + a] = (float)((sl[m] << 2) | (lab + 1));

    float4 mb = sb[m];
    float sw = av[k].z - av[k].x, sh2 = av[k].w - av[k].y;
    float sx = av[k].x + 0.5f*sw, sy = av[k].y + 0.5f*sh2;
    float tw = mb.z - mb.x,       th = mb.w - mb.y;
    float tx = mb.x + 0.5f*tw,    ty = mb.y + 0.5f*th;
    float4 d;
    d.x = (tx - sx) / sw;
    d.y = (ty - sy) / sh2;
    d.z = logf(tw / sw);
    d.w = logf(th / sh2);
    *(float4*)(out + (size_t)NB * A + ((size_t)b * A + a) * 4) = d;
  }
}

// K3: per (b,t): g = max_blk bmax; rescan only attaining blocks (expected ~1)
// and set the high-bit for anchors with v == g (bit-exact recompute).
__global__ __launch_bounds__(256) void k3(const float4* __restrict__ anchors,
                                          const float4* __restrict__ boxes,
                                          const int* __restrict__ bmax,
                                          unsigned* __restrict__ highmask,
                                          int A, int NBLK, int WPI) {
  int bt = blockIdx.x;            // b*64 + t
  int b = bt >> 6;
  int tid = threadIdx.x;
  const int* bm = bmax + (size_t)bt * NBLK;

  __shared__ int red[256];
  __shared__ int lst[256];
  __shared__ int cnt;
  int mv = 0;
  for (int i = tid; i < NBLK; i += 256) mv = max(mv, bm[i]);
  red[tid] = mv;
  if (tid == 0) cnt = 0;
  __syncthreads();
  for (int s = 128; s > 0; s >>= 1) {
    if (tid < s) red[tid] = max(red[tid], red[tid + s]);
    __syncthreads();
  }
  int g = red[0];

  for (int i = tid; i < NBLK; i += 256)
    if (bm[i] == g) { int p = atomicAdd(&cnt, 1); lst[p] = i; }
  __syncthreads();

  float4 bb = boxes[bt];
  float at = (bb.z - bb.x) * (bb.w - bb.y);
  int n = cnt;
  for (int j = 0; j < n; ++j) {
    int blk = lst[j];
#pragma unroll
    for (int q = 0; q < K1_APB; q += 256) {
      int a = blk * K1_APB + q + tid;
      if (a < A) {
        float4 av = anchors[a];
        float aar = (av.z - av.x) * (av.w - av.y);
        float v = iou_exact(bb, at, av, aar);
        if (__float_as_int(v) == g)
          atomicOr(highmask + (size_t)b * WPI + (a >> 5), 1u << (a & 31));
      }
    }
  }
}

// K4: finalize labels from code word + high bit.
__global__ __launch_bounds__(256) void k4(const unsigned* __restrict__ highmask,
                                          float* __restrict__ out, int A, int WPI) {
  int a = blockIdx.x * 256 + threadIdx.x;
  int b = blockIdx.y;
  if (a >= A) return;
  int code = (int)out[(size_t)b * A + a];
  bool high = (highmask[(size_t)b * WPI + (a >> 5)] >> (a & 31)) & 1u;
  int lab = (code & 3) - 1;
  float o;
  if (high || lab == 1) o = (float)(code >> 2);       // positive: gt label
  else if (lab == 0)    o = (float)NUM_CLASSES;       // background
  else                  o = -1.0f;                    // ignore
  out[(size_t)b * A + a] = o;
}

extern "C" void kernel_launch(void* const* d_in, const int* in_sizes, int n_in,
                              void* d_out, int out_size, void* d_ws, size_t ws_size,
                              hipStream_t stream) {
  const float* anchors    = (const float*)d_in[0];
  const float* tgt_boxes  = (const float*)d_in[1];
  const int*   tgt_labels = (const int*)d_in[2];
  int A = in_sizes[0] / 4;
  int NBLK = (A + K1_APB - 1) / K1_APB;     // 235
  int WPI  = (A + 31) / 32;                 // high-bitmask words per image

  char* ws = (char*)d_ws;
  float4*   boxes    = (float4*)ws;                              // NB*TB*16 B
  int*      bmax     = (int*)(ws + NB * TB * 16);                // NB*TB*NBLK*4 B
  unsigned* highmask = (unsigned*)(ws + NB * TB * 16 + (size_t)NB * TB * NBLK * 4);
  float*    out      = (float*)d_out;

  hipMemsetAsync(highmask, 0, (size_t)NB * WPI * 4, stream);
  pass0<<<2, 256, 0, stream>>>(tgt_boxes, boxes);
  dim3 g1(NBLK, NB);
  k1<<<g1, 256, 0, stream>>>((const float4*)anchors, boxes, tgt_labels,
                             bmax, out, A, NBLK);
  k3<<<NB * TB, 256, 0, stream>>>((const float4*)anchors, boxes, bmax,
                                  highmask, A, NBLK, WPI);
  dim3 g4((A + 255) / 256, NB);
  k4<<<g4, 256, 0, stream>>>(highmask, out, A, WPI);
}

// Round 7
// 91.797 us; speedup vs baseline: 1.9825x; 1.1037x over previous
//
#include <hip/hip_runtime.h>
#include <math.h>

// FP contraction off: every f32 op is an exactly-rounded IEEE op in fixed
// order -> IoU and box conversion are bit-identical in k1 and k3, and match
// the numpy float32 reference (per-element rounded div, then max/argmax).
#pragma clang fp contract(off)

#define NUM_CLASSES 80
#define TB 64
#define NB 8
#define K1_T 512              // threads per k1 block
#define K1_K 2                // anchors per thread
#define K1_APB (K1_T * K1_K)  // 1024 anchors per block
#define K1_WAVES (K1_T / 64)  // 8

// The one-and-only IoU expression (identical in k1 and k3's rescan).
__device__ __forceinline__ float iou_exact(const float4 bb, float at,
                                           const float4 av, float aar) {
  float w = fminf(bb.z, av.z) - fmaxf(bb.x, av.x);
  float h = fminf(bb.w, av.w) - fmaxf(bb.y, av.y);
  w = fmaxf(w, 0.0f);
  h = fmaxf(h, 0.0f);
  float inter = w * h;
  float u = (at + aar) - inter;
  return inter / u;   // correctly-rounded IEEE f32 div
}

// cxcywh -> xyxy (identical expression wherever boxes are needed).
__device__ __forceinline__ float4 box_from_tgt(const float* tp) {
  float cx = tp[0], cy = tp[1], w = tp[2], h = tp[3];
  return make_float4(cx - 0.5f*w, cy - 0.5f*h, cx + 0.5f*w, cy + 0.5f*h);
}

// TWO interleaved wave64 max-reduce DPP chains (non-negative inputs;
// bound_ctrl=1 feeds 0.0f). Interleaving fills the DPP RAW-hazard wait
// states with the sibling chain's ops. Results in lane 63.
__device__ __forceinline__ void wave_max2_nonneg(float& a, float& b) {
  int va = __float_as_int(a), vb = __float_as_int(b);
#define ST(ctrl)                                                            \
  { int ta = __builtin_amdgcn_update_dpp(0, va, ctrl, 0xf, 0xf, true);      \
    int tb = __builtin_amdgcn_update_dpp(0, vb, ctrl, 0xf, 0xf, true);      \
    va = __float_as_int(fmaxf(__int_as_float(va), __int_as_float(ta)));     \
    vb = __float_as_int(fmaxf(__int_as_float(vb), __int_as_float(tb))); }
  ST(0x111) ST(0x112) ST(0x114) ST(0x118) ST(0x142) ST(0x143)
#undef ST
  a = __int_as_float(va); b = __int_as_float(vb);
}

// K1: per (b, anchor): argmax/max over t (plain div); per t, interleaved
// DPP wave-max -> per-wave LDS slot -> block max -> bmax. Also computes
// boxes from tgt (no pass0), zeroes its highmask slice (no memset), writes
// final deltas + temporary label-code into out.
__global__ __launch_bounds__(K1_T) void k1(const float4* __restrict__ anchors,
                                           const float* __restrict__ tgt,
                                           const int* __restrict__ labels,
                                           int* __restrict__ bmax,
                                           unsigned* __restrict__ highmask,
                                           float* __restrict__ out,
                                           int A, int NBLK, int WPI) {
  int b = blockIdx.y;
  __shared__ float4 sb[TB];
  __shared__ float  sa[TB];
  __shared__ int    sl[TB];
  __shared__ float  swm[K1_WAVES][TB];
  int tid = threadIdx.x;
  if (tid < TB) {
    float4 bv = box_from_tgt(tgt + (b * TB + tid) * 4);
    sb[tid] = bv;
    sa[tid] = (bv.z - bv.x) * (bv.w - bv.y);
    sl[tid] = labels[b * TB + tid];
  }
  // zero this block's highmask slice (k3 atomicOr's into it afterwards)
  {
    int nw = K1_APB / 32;   // 32 words
    if (tid < nw) {
      int w0 = blockIdx.x * nw + tid;
      if (w0 < WPI) highmask[(size_t)b * WPI + w0] = 0u;
    }
  }
  __syncthreads();

  int lane = tid & 63, wid = tid >> 6;
  int abase = blockIdx.x * K1_APB + tid;
  int a0c = min(abase, A - 1);            // dup clamp: benign for max
  int a1c = min(abase + K1_T, A - 1);
  float4 av0 = anchors[a0c], av1 = anchors[a1c];
  float aar0 = (av0.z - av0.x) * (av0.w - av0.y);
  float aar1 = (av1.z - av1.x) * (av1.w - av1.y);
  float best0 = -1.0f, best1 = -1.0f;
  int mid0 = 0, mid1 = 0;

  for (int t = 0; t < TB; t += 2) {
    float4 bbA = sb[t];     float atA = sa[t];
    float4 bbB = sb[t + 1]; float atB = sa[t + 1];
    float vA0 = iou_exact(bbA, atA, av0, aar0);
    float vA1 = iou_exact(bbA, atA, av1, aar1);
    float vB0 = iou_exact(bbB, atB, av0, aar0);
    float vB1 = iou_exact(bbB, atB, av1, aar1);
    // t before t+1: strict > keeps argmax first-occurrence
    if (vA0 > best0) { best0 = vA0; mid0 = t; }
    if (vA1 > best1) { best1 = vA1; mid1 = t; }
    if (vB0 > best0) { best0 = vB0; mid0 = t + 1; }
    if (vB1 > best1) { best1 = vB1; mid1 = t + 1; }
    float mA = fmaxf(vA0, vA1);
    float mB = fmaxf(vB0, vB1);
    wave_max2_nonneg(mA, mB);
    if (lane == 63) { swm[wid][t] = mA; swm[wid][t + 1] = mB; }
  }
  __syncthreads();
  if (tid < TB) {
    float m = swm[0][tid];
#pragma unroll
    for (int w = 1; w < K1_WAVES; ++w) m = fmaxf(m, swm[w][tid]);
    bmax[(size_t)(b * TB + tid) * NBLK + blockIdx.x] = __float_as_int(m);
  }

#pragma unroll
  for (int k = 0; k < K1_K; ++k) {
    int a = abase + k * K1_T;
    if (a >= A) continue;
    float4 avk = k ? av1 : av0;
    float M    = k ? best1 : best0;
    int   m    = k ? mid1 : mid0;
    int lab = (M >= 0.5f) ? 1 : ((M >= 0.4f) ? -1 : 0);
    // temporary code word; final label needs `high` (k3/k4)
    out[(size_t)b * A + a] = (float)((sl[m] << 2) | (lab + 1));

    float4 mb = sb[m];
    float sw = avk.z - avk.x, sh2 = avk.w - avk.y;
    float sx = avk.x + 0.5f * sw, sy = avk.y + 0.5f * sh2;
    float tw = mb.z - mb.x,       th = mb.w - mb.y;
    float tx = mb.x + 0.5f * tw,  ty = mb.y + 0.5f * th;
    float4 d;
    d.x = (tx - sx) / sw;
    d.y = (ty - sy) / sh2;
    d.z = logf(tw / sw);
    d.w = logf(th / sh2);
    *(float4*)(out + (size_t)NB * A + ((size_t)b * A + a) * 4) = d;
  }
}

// K3: per (b,t): g = max_blk bmax; rescan only attaining blocks (expected ~1)
// and set the high-bit for anchors with v == g (bit-exact recompute).
__global__ __launch_bounds__(256) void k3(const float4* __restrict__ anchors,
                                          const float* __restrict__ tgt,
                                          const int* __restrict__ bmax,
                                          unsigned* __restrict__ highmask,
                                          int A, int NBLK, int WPI) {
  int bt = blockIdx.x, b = bt >> 6;
  const int* bm = bmax + (size_t)bt * NBLK;
  __shared__ int red[256];
  __shared__ int lst[128];
  __shared__ int cnt;
  int tid = threadIdx.x;
  red[tid] = (tid < NBLK) ? bm[tid] : 0;
  if (tid == 0) cnt = 0;
  __syncthreads();
  for (int s = 128; s > 0; s >>= 1) {
    if (tid < s) red[tid] = max(red[tid], red[tid + s]);
    __syncthreads();
  }
  int g = red[0];
  if (tid < NBLK && bm[tid] == g) {
    int p = atomicAdd(&cnt, 1);
    if (p < 128) lst[p] = tid;
  }
  __syncthreads();

  float4 bb = box_from_tgt(tgt + bt * 4);   // bit-identical to k1's sb
  float at = (bb.z - bb.x) * (bb.w - bb.y);
  int n = min(cnt, 128);
  for (int j = 0; j < n; ++j) {
    int blk = lst[j];
#pragma unroll
    for (int q = 0; q < K1_APB; q += 256) {
      int a = blk * K1_APB + q + tid;
      if (a < A) {
        float4 av = anchors[a];
        float aar = (av.z - av.x) * (av.w - av.y);
        float v = iou_exact(bb, at, av, aar);
        if (__float_as_int(v) == g)
          atomicOr(highmask + (size_t)b * WPI + (a >> 5), 1u << (a & 31));
      }
    }
  }
}

// K4: finalize labels from code word + high bit.
__global__ __launch_bounds__(256) void k4(const unsigned* __restrict__ highmask,
                                          float* __restrict__ out, int A, int WPI) {
  int a = blockIdx.x * 256 + threadIdx.x;
  int b = blockIdx.y;
  if (a >= A) return;
  int code = (int)out[(size_t)b * A + a];
  bool high = (highmask[(size_t)b * WPI + (a >> 5)] >> (a & 31)) & 1u;
  int lab = (code & 3) - 1;
  float o;
  if (high || lab == 1) o = (float)(code >> 2);   // positive: gt label
  else if (lab == 0)    o = (float)NUM_CLASSES;   // background
  else                  o = -1.0f;                // ignore
  out[(size_t)b * A + a] = o;
}

extern "C" void kernel_launch(void* const* d_in, const int* in_sizes, int n_in,
                              void* d_out, int out_size, void* d_ws, size_t ws_size,
                              hipStream_t stream) {
  const float* anchors    = (const float*)d_in[0];
  const float* tgt_boxes  = (const float*)d_in[1];
  const int*   tgt_labels = (const int*)d_in[2];
  int A = in_sizes[0] / 4;
  int NBLK = (A + K1_APB - 1) / K1_APB;   // 118
  int WPI  = (A + 31) / 32;               // highmask words per image

  char* ws = (char*)d_ws;
  int*      bmax     = (int*)ws;                               // NB*TB*NBLK ints
  unsigned* highmask = (unsigned*)(ws + (size_t)NB * TB * NBLK * 4);
  float*    out      = (float*)d_out;

  dim3 g1(NBLK, NB);
  k1<<<g1, K1_T, 0, stream>>>((const float4*)anchors, tgt_boxes, tgt_labels,
                              bmax, highmask, out, A, NBLK, WPI);
  k3<<<NB * TB, 256, 0, stream>>>((const float4*)anchors, tgt_boxes, bmax,
                                  highmask, A, NBLK, WPI);
  dim3 g4((A + 255) / 256, NB);
  k4<<<g4, 256, 0, stream>>>(highmask, out, A, WPI);
}